// Round 1
// baseline (717.890 us; speedup 1.0000x reference)
//
#include <hip/hip_runtime.h>
#include <hip/hip_bf16.h>

#define S 64
#define HF 128
#define WF 128
#define CCH 256
#define NBOX 128                      // B * N
#define CROPS_ELEMS (134217728)      // NBOX * CCH * S * S

// ---------------- Kernel A: per-box theta + M ----------------
__global__ void prep_kernel(const float* __restrict__ obb,
                            float* __restrict__ theta_ws,
                            float* __restrict__ m_out) {
    int i = blockIdx.x * blockDim.x + threadIdx.x;
    if (i >= NBOX) return;
    const float* o = obb + i * 5;
    float cx = o[0], cy = o[1], w = o[2], h = o[3], deg = o[4];
    float cxf = cx * 0.125f;
    float cyf = cy * 0.125f;
    float wf = fmaxf(w, 1.0f) * 1.25f * 0.125f;
    float hf = fmaxf(h, 1.0f) * 1.25f * 0.125f;
    float ang = deg * 0.017453292519943295f;  // deg2rad
    float c_ = cosf(ang);
    float s_ = sinf(ang);
    float sx = wf * (2.0f / (float)WF);
    float sy = hf * (2.0f / (float)HF);
    float tx = cxf * (2.0f / (float)WF) - 1.0f;
    float ty = cyf * (2.0f / (float)HF) - 1.0f;
    float* th = theta_ws + i * 6;
    th[0] = c_ * sx;  th[1] = -s_ * sy; th[2] = tx;
    th[3] = s_ * sx;  th[4] = c_ * sy;  th[5] = ty;

    float A  = c_ * (wf / (float)S);
    float Bv = -s_ * (hf / (float)S);
    float A2 = s_ * (wf / (float)S);
    float B2 = c_ * (hf / (float)S);
    float Cx = cxf - 0.5f * (float)S * (A + Bv);
    float Cy = cyf - 0.5f * (float)S * (A2 + B2);
    float* m = m_out + i * 6;
    m[0] = A;  m[1] = Bv; m[2] = Cx;
    m[3] = A2; m[4] = B2; m[5] = Cy;
}

// ---------------- Kernel B: bilinear sampling ----------------
// grid: 128 boxes * 16 row-tiles; block: 256 threads = 4 rows x 64 cols.
__global__ __launch_bounds__(256) void sample_kernel(
        const float* __restrict__ feat,
        const float* __restrict__ theta,
        float* __restrict__ out) {
    int box   = blockIdx.x >> 4;
    int ytile = blockIdx.x & 15;
    int tid = threadIdx.x;
    int x = tid & 63;
    int y = (ytile << 2) + (tid >> 6);

    const float* th = theta + box * 6;
    float t00 = th[0], t01 = th[1], t02 = th[2];
    float t10 = th[3], t11 = th[4], t12 = th[5];

    float bx = (float)(2 * x + 1) * (1.0f / (float)S) - 1.0f;
    float by = (float)(2 * y + 1) * (1.0f / (float)S) - 1.0f;
    float gx = t00 * bx + t01 * by + t02;
    float gy = t10 * bx + t11 * by + t12;

    float ix = ((gx + 1.0f) * (float)WF - 1.0f) * 0.5f;
    float iy = ((gy + 1.0f) * (float)HF - 1.0f) * 0.5f;
    float x0f = floorf(ix);
    float y0f = floorf(iy);
    int x0 = (int)x0f;
    int y0 = (int)y0f;
    float wx1 = ix - x0f;
    float wy1 = iy - y0f;
    float wx0 = 1.0f - wx1;
    float wy0 = 1.0f - wy1;
    int x1 = x0 + 1;
    int y1 = y0 + 1;

    bool vx0 = (x0 >= 0) & (x0 < WF);
    bool vx1 = (x1 >= 0) & (x1 < WF);
    bool vy0 = (y0 >= 0) & (y0 < HF);
    bool vy1 = (y1 >= 0) & (y1 < HF);

    float w00 = (vx0 & vy0) ? wx0 * wy0 : 0.0f;
    float w10 = (vx1 & vy0) ? wx1 * wy0 : 0.0f;
    float w01 = (vx0 & vy1) ? wx0 * wy1 : 0.0f;
    float w11 = (vx1 & vy1) ? wx1 * wy1 : 0.0f;

    int x0c = min(max(x0, 0), WF - 1);
    int x1c = min(max(x1, 0), WF - 1);
    int y0c = min(max(y0, 0), HF - 1);
    int y1c = min(max(y1, 0), HF - 1);

    int off00 = y0c * WF + x0c;
    int off10 = y0c * WF + x1c;
    int off01 = y1c * WF + x0c;
    int off11 = y1c * WF + x1c;

    const float* fmb = feat + (size_t)(box >> 6) * (size_t)(CCH * HF * WF);
    float* op = out + (size_t)box * (size_t)(CCH * S * S) + y * S + x;

#pragma unroll 4
    for (int c = 0; c < CCH; ++c) {
        const float* p = fmb + c * (HF * WF);
        float v = p[off00] * w00 + p[off10] * w10
                + p[off01] * w01 + p[off11] * w11;
        op[(size_t)c * (S * S)] = v;
    }
}

extern "C" void kernel_launch(void* const* d_in, const int* in_sizes, int n_in,
                              void* d_out, int out_size, void* d_ws, size_t ws_size,
                              hipStream_t stream) {
    const float* feat = (const float*)d_in[0];
    const float* obb  = (const float*)d_in[1];
    float* out = (float*)d_out;
    float* theta_ws = (float*)d_ws;
    float* m_out = out + CROPS_ELEMS;

    prep_kernel<<<1, 128, 0, stream>>>(obb, theta_ws, m_out);
    sample_kernel<<<2048, 256, 0, stream>>>(feat, theta_ws, out);
}

// Round 2
// 302.523 us; speedup vs baseline: 2.3730x; 2.3730x over previous
//
#include <hip/hip_runtime.h>
#include <hip/hip_bf16.h>

#define S 64
#define HF 128
#define WF 128
#define CCH 256
#define NBOX 128                      // B * N
#define CROPS_ELEMS (134217728)      // NBOX * CCH * S * S
#define CHG 16                        // channels per block
#define NGRP (CCH / CHG)              // 16 channel groups
#define TILE_CAP 15000                // floats (60 KB) -> 2 blocks/CU; worst tile <= ~115x115=13225

// ---------------- Kernel A: per-box theta + M ----------------
__global__ void prep_kernel(const float* __restrict__ obb,
                            float* __restrict__ theta_ws,
                            float* __restrict__ m_out) {
    int i = blockIdx.x * blockDim.x + threadIdx.x;
    if (i >= NBOX) return;
    const float* o = obb + i * 5;
    float cx = o[0], cy = o[1], w = o[2], h = o[3], deg = o[4];
    float cxf = cx * 0.125f;
    float cyf = cy * 0.125f;
    float wf = fmaxf(w, 1.0f) * 1.25f * 0.125f;
    float hf = fmaxf(h, 1.0f) * 1.25f * 0.125f;
    float ang = deg * 0.017453292519943295f;  // deg2rad
    float c_ = cosf(ang);
    float s_ = sinf(ang);
    float sx = wf * (2.0f / (float)WF);
    float sy = hf * (2.0f / (float)HF);
    float tx = cxf * (2.0f / (float)WF) - 1.0f;
    float ty = cyf * (2.0f / (float)HF) - 1.0f;
    float* th = theta_ws + i * 6;
    th[0] = c_ * sx;  th[1] = -s_ * sy; th[2] = tx;
    th[3] = s_ * sx;  th[4] = c_ * sy;  th[5] = ty;

    float A  = c_ * (wf / (float)S);
    float Bv = -s_ * (hf / (float)S);
    float A2 = s_ * (wf / (float)S);
    float B2 = c_ * (hf / (float)S);
    float Cx = cxf - 0.5f * (float)S * (A + Bv);
    float Cy = cyf - 0.5f * (float)S * (A2 + B2);
    float* m = m_out + i * 6;
    m[0] = A;  m[1] = Bv; m[2] = Cx;
    m[3] = A2; m[4] = B2; m[5] = Cy;
}

// ---------------- Kernel B: LDS-tiled bilinear sampling ----------------
// grid: NBOX * NGRP blocks; block handles one box x CHG channels, full 64x64 crop.
__global__ __launch_bounds__(256) void sample_kernel(
        const float* __restrict__ feat,
        const float* __restrict__ theta,
        float* __restrict__ out) {
    __shared__ float tile[TILE_CAP];

    const int box = blockIdx.x >> 4;      // / NGRP
    const int grp = blockIdx.x & 15;      // % NGRP
    const int tid = threadIdx.x;

    const float* th = theta + box * 6;
    // feature-pixel affine: ix = ax*fx + bxc*fy + cx_, where fx,fy in [-63/64, 63/64]
    float ax  = th[0] * 64.0f, bxc = th[1] * 64.0f, cx_ = th[2] * 64.0f + 63.5f;
    float ay  = th[3] * 64.0f, byc = th[4] * 64.0f, cy_ = th[5] * 64.0f + 63.5f;

    // bounding box of all sample coordinates (+1 for bilinear upper corner)
    float hx = (fabsf(ax) + fabsf(bxc)) * (63.0f / 64.0f);
    float hy = (fabsf(ay) + fabsf(byc)) * (63.0f / 64.0f);
    int tx0 = min(max((int)floorf(cx_ - hx), 0), WF - 1);
    int tx1 = min(max((int)floorf(cx_ + hx) + 1, 0), WF - 1);
    int ty0 = min(max((int)floorf(cy_ - hy), 0), HF - 1);
    int ty1 = min(max((int)floorf(cy_ + hy) + 1, 0), HF - 1);
    int tw  = tx1 - tx0 + 1;
    int thh = ty1 - ty0 + 1;
    int twp = tw | 1;                     // odd LDS row stride (bank-conflict insurance)
    int n   = tw * thh;

    // per-pixel channel-invariant sampling params, cached in registers
    int   pk [16];
    float W00[16], W10[16], W01[16], W11[16];
#pragma unroll
    for (int it = 0; it < 16; ++it) {
        int px = tid + (it << 8);
        int x = px & 63, y = px >> 6;
        float fx = (float)(2 * x + 1) * 0.015625f - 1.0f;
        float fy = (float)(2 * y + 1) * 0.015625f - 1.0f;
        float ix = ax * fx + bxc * fy + cx_;
        float iy = ay * fx + byc * fy + cy_;
        float x0f = floorf(ix), y0f = floorf(iy);
        int x0 = (int)x0f, y0 = (int)y0f;
        float wx1 = ix - x0f, wy1 = iy - y0f;
        float wx0 = 1.0f - wx1, wy0 = 1.0f - wy1;
        bool vx0 = (x0 >= 0) & (x0 < WF);
        bool vx1 = (x0 >= -1) & (x0 < WF - 1);
        bool vy0 = (y0 >= 0) & (y0 < HF);
        bool vy1 = (y0 >= -1) & (y0 < HF - 1);
        W00[it] = (vx0 & vy0) ? wx0 * wy0 : 0.0f;
        W10[it] = (vx1 & vy0) ? wx1 * wy0 : 0.0f;
        W01[it] = (vx0 & vy1) ? wx0 * wy1 : 0.0f;
        W11[it] = (vx1 & vy1) ? wx1 * wy1 : 0.0f;
        int x0c = min(max(x0, 0), WF - 1) - tx0;
        int y0c = min(max(y0, 0), HF - 1) - ty0;
        int x1c = min(max(x0 + 1, 0), WF - 1) - tx0;
        int y1c = min(max(y0 + 1, 0), HF - 1) - ty0;
        int xs = x1c - x0c;               // 0 or 1
        int ys = y1c - y0c;               // 0 or 1
        pk[it] = (y0c * twp + x0c) | (xs << 16) | (ys << 17);
    }

    // tile-loader per-thread walking state (no division in the loop)
    int qy0 = tid / tw;
    int qx0 = tid - qy0 * tw;
    int kq  = 256 / tw;
    int rq  = 256 - kq * tw;
    int lidx0 = qy0 * twp + qx0;
    int gidx0 = (ty0 + qy0) * WF + tx0 + qx0;
    int stepL = kq * twp + rq;
    int stepG = (kq << 7) + rq;

    const float* fmb = feat + (size_t)(box >> 6) * (size_t)(CCH * HF * WF)
                            + (size_t)(grp * CHG) * (HF * WF);
    float* ob = out + (size_t)box * (size_t)(CCH * S * S)
                    + (size_t)(grp * CHG) * (S * S) + tid;

    for (int ch = 0; ch < CHG; ++ch) {
        const float* fc = fmb + ch * (HF * WF);
        // ---- stage tile (coalesced row segments) ----
        {
            int qx = qx0, lidx = lidx0, gidx = gidx0;
            for (int q = tid; q < n; q += 256) {
                tile[lidx] = fc[gidx];
                qx += rq; lidx += stepL; gidx += stepG;
                if (qx >= tw) { qx -= tw; lidx += twp - tw; gidx += WF - tw; }
            }
        }
        __syncthreads();
        // ---- sample 16 pixels/thread from LDS ----
        float* oc = ob + ch * (S * S);
#pragma unroll
        for (int it = 0; it < 16; ++it) {
            int p   = pk[it];
            int a00 = p & 0xFFFF;
            int xs  = (p >> 16) & 1;
            int a01 = a00 + (((p >> 17) & 1) ? twp : 0);
            float v = tile[a00]      * W00[it] + tile[a00 + xs] * W10[it]
                    + tile[a01]      * W01[it] + tile[a01 + xs] * W11[it];
            oc[it << 8] = v;
        }
        __syncthreads();
    }
}

extern "C" void kernel_launch(void* const* d_in, const int* in_sizes, int n_in,
                              void* d_out, int out_size, void* d_ws, size_t ws_size,
                              hipStream_t stream) {
    const float* feat = (const float*)d_in[0];
    const float* obb  = (const float*)d_in[1];
    float* out = (float*)d_out;
    float* theta_ws = (float*)d_ws;
    float* m_out = out + CROPS_ELEMS;

    prep_kernel<<<1, 128, 0, stream>>>(obb, theta_ws, m_out);
    sample_kernel<<<NBOX * NGRP, 256, 0, stream>>>(feat, theta_ws, out);
}

// Round 3
// 199.274 us; speedup vs baseline: 3.6025x; 1.5181x over previous
//
#include <hip/hip_runtime.h>
#include <hip/hip_bf16.h>

#define S 64
#define HF 128
#define WF 128
#define CCH 256
#define NBOX 128                      // B * N
#define CROPS_ELEMS (134217728)      // NBOX * CCH * S * S
#define CHG 16                        // channels per block
#define NGRP (CCH / CHG)              // 16 channel groups
#define TILE_CAP 3600                 // floats (14.4 KB); worst quadrant tile <= ~58x58=3364

// ---------------- Kernel A: per-box theta + M ----------------
__global__ void prep_kernel(const float* __restrict__ obb,
                            float* __restrict__ theta_ws,
                            float* __restrict__ m_out) {
    int i = blockIdx.x * blockDim.x + threadIdx.x;
    if (i >= NBOX) return;
    const float* o = obb + i * 5;
    float cx = o[0], cy = o[1], w = o[2], h = o[3], deg = o[4];
    float cxf = cx * 0.125f;
    float cyf = cy * 0.125f;
    float wf = fmaxf(w, 1.0f) * 1.25f * 0.125f;
    float hf = fmaxf(h, 1.0f) * 1.25f * 0.125f;
    float ang = deg * 0.017453292519943295f;  // deg2rad
    float c_ = cosf(ang);
    float s_ = sinf(ang);
    float sx = wf * (2.0f / (float)WF);
    float sy = hf * (2.0f / (float)HF);
    float tx = cxf * (2.0f / (float)WF) - 1.0f;
    float ty = cyf * (2.0f / (float)HF) - 1.0f;
    float* th = theta_ws + i * 6;
    th[0] = c_ * sx;  th[1] = -s_ * sy; th[2] = tx;
    th[3] = s_ * sx;  th[4] = c_ * sy;  th[5] = ty;

    float A  = c_ * (wf / (float)S);
    float Bv = -s_ * (hf / (float)S);
    float A2 = s_ * (wf / (float)S);
    float B2 = c_ * (hf / (float)S);
    float Cx = cxf - 0.5f * (float)S * (A + Bv);
    float Cy = cyf - 0.5f * (float)S * (A2 + B2);
    float* m = m_out + i * 6;
    m[0] = A;  m[1] = Bv; m[2] = Cx;
    m[3] = A2; m[4] = B2; m[5] = Cy;
}

// ---------------- Kernel B: LDS-tiled bilinear sampling, quadrant blocks ----
// grid: NBOX * 4 quadrants * NGRP; block = 256 threads = 32 rows x 8 groups of
// 4 consecutive x pixels (float4 stores). One 32x32 crop quadrant, CHG channels.
__global__ __launch_bounds__(256, 8) void sample_kernel(
        const float* __restrict__ feat,
        const float* __restrict__ theta,
        float* __restrict__ out) {
    __shared__ float tile[TILE_CAP];

    const int b    = blockIdx.x;
    const int grp  = b & 15;              // % NGRP
    const int quad = (b >> 4) & 3;
    const int box  = b >> 6;
    const int qx   = quad & 1;
    const int qy   = quad >> 1;
    const int tid  = threadIdx.x;

    const float* th = theta + box * 6;
    // feature-pixel affine: ix = ax*fx + bxc*fy + cx_, fx,fy in (-1,1)
    float ax  = th[0] * 64.0f, bxc = th[1] * 64.0f, cx_ = th[2] * 64.0f + 63.5f;
    float ay  = th[3] * 64.0f, byc = th[4] * 64.0f, cy_ = th[5] * 64.0f + 63.5f;

    // quadrant sample-coordinate bbox (+1 for bilinear upper corner)
    float fcx = (float)qx - 0.5f;         // center of quadrant in fx
    float fcy = (float)qy - 0.5f;
    float fh  = 31.0f / 64.0f;            // half-range
    float cxq = ax * fcx + bxc * fcy + cx_;
    float cyq = ay * fcx + byc * fcy + cy_;
    float hxq = (fabsf(ax) + fabsf(bxc)) * fh;
    float hyq = (fabsf(ay) + fabsf(byc)) * fh;
    int tx0 = min(max((int)floorf(cxq - hxq), 0), WF - 1);
    int tx1 = min(max((int)floorf(cxq + hxq) + 1, 0), WF - 1);
    int ty0 = min(max((int)floorf(cyq - hyq), 0), HF - 1);
    int ty1 = min(max((int)floorf(cyq + hyq) + 1, 0), HF - 1);
    int tw  = tx1 - tx0 + 1;
    int thh = ty1 - ty0 + 1;
    int twp = tw | 1;                     // odd LDS row stride
    int n   = tw * thh;

    // this thread's 4 consecutive-x pixels
    const int r     = tid >> 3;           // 0..31 (row within quadrant)
    const int g     = tid & 7;            // 0..7
    const int y     = (qy << 5) + r;
    const int xbase = (qx << 5) + (g << 2);

    int   pk [4];
    float W00[4], W10[4], W01[4], W11[4];
    {
        float fy = (float)(2 * y + 1) * 0.015625f - 1.0f;
#pragma unroll
        for (int j = 0; j < 4; ++j) {
            int x = xbase + j;
            float fx = (float)(2 * x + 1) * 0.015625f - 1.0f;
            float ix = ax * fx + bxc * fy + cx_;
            float iy = ay * fx + byc * fy + cy_;
            float x0f = floorf(ix), y0f = floorf(iy);
            int x0 = (int)x0f, y0 = (int)y0f;
            float wx1 = ix - x0f, wy1 = iy - y0f;
            float wx0 = 1.0f - wx1, wy0 = 1.0f - wy1;
            bool vx0 = (x0 >= 0) & (x0 < WF);
            bool vx1 = (x0 >= -1) & (x0 < WF - 1);
            bool vy0 = (y0 >= 0) & (y0 < HF);
            bool vy1 = (y0 >= -1) & (y0 < HF - 1);
            W00[j] = (vx0 & vy0) ? wx0 * wy0 : 0.0f;
            W10[j] = (vx1 & vy0) ? wx1 * wy0 : 0.0f;
            W01[j] = (vx0 & vy1) ? wx0 * wy1 : 0.0f;
            W11[j] = (vx1 & vy1) ? wx1 * wy1 : 0.0f;
            int x0c = min(max(x0, 0), WF - 1) - tx0;
            int y0c = min(max(y0, 0), HF - 1) - ty0;
            int x1c = min(max(x0 + 1, 0), WF - 1) - tx0;
            int y1c = min(max(y0 + 1, 0), HF - 1) - ty0;
            int xs = x1c - x0c;           // 0 or 1
            int ys = y1c - y0c;           // 0 or 1
            pk[j] = (y0c * twp + x0c) | (xs << 16) | (ys << 17);
        }
    }

    // tile-loader walking state (no division in the channel loop)
    int qy0_ = tid / tw;
    int qx0_ = tid - qy0_ * tw;
    int kq   = 256 / tw;
    int rq   = 256 - kq * tw;
    int lidx0 = qy0_ * twp + qx0_;
    int gidx0 = (ty0 + qy0_) * WF + tx0 + qx0_;
    int stepL = kq * twp + rq;
    int stepG = (kq << 7) + rq;

    const float* fmb = feat + (size_t)(box >> 6) * (size_t)(CCH * HF * WF)
                            + (size_t)(grp * CHG) * (HF * WF);
    float* ob = out + (size_t)box * (size_t)(CCH * S * S)
                    + (size_t)(grp * CHG) * (S * S) + y * S + xbase;

    for (int ch = 0; ch < CHG; ++ch) {
        const float* fc = fmb + ch * (HF * WF);
        // ---- stage tile (coalesced row segments) ----
        {
            int qx_ = qx0_, lidx = lidx0, gidx = gidx0;
            for (int q = tid; q < n; q += 256) {
                tile[lidx] = fc[gidx];
                qx_ += rq; lidx += stepL; gidx += stepG;
                if (qx_ >= tw) { qx_ -= tw; lidx += twp - tw; gidx += WF - tw; }
            }
        }
        __syncthreads();
        // ---- sample 4 consecutive pixels, store float4 ----
        float4 v;
        float* vp = &v.x;
#pragma unroll
        for (int j = 0; j < 4; ++j) {
            int p   = pk[j];
            int a00 = p & 0xFFFF;
            int xs  = (p >> 16) & 1;
            int a01 = a00 + (((p >> 17) & 1) ? twp : 0);
            vp[j] = tile[a00]      * W00[j] + tile[a00 + xs] * W10[j]
                  + tile[a01]      * W01[j] + tile[a01 + xs] * W11[j];
        }
        *reinterpret_cast<float4*>(ob + (size_t)ch * (S * S)) = v;
        __syncthreads();
    }
}

extern "C" void kernel_launch(void* const* d_in, const int* in_sizes, int n_in,
                              void* d_out, int out_size, void* d_ws, size_t ws_size,
                              hipStream_t stream) {
    const float* feat = (const float*)d_in[0];
    const float* obb  = (const float*)d_in[1];
    float* out = (float*)d_out;
    float* theta_ws = (float*)d_ws;
    float* m_out = out + CROPS_ELEMS;

    prep_kernel<<<1, 128, 0, stream>>>(obb, theta_ws, m_out);
    sample_kernel<<<NBOX * 4 * NGRP, 256, 0, stream>>>(feat, theta_ws, out);
}